// Round 5
// baseline (113.398 us; speedup 1.0000x reference)
//
#include <hip/hip_runtime.h>
#include <stdint.h>

typedef short bf16x8 __attribute__((ext_vector_type(8)));
typedef float f32x4 __attribute__((ext_vector_type(4)));

__device__ __forceinline__ unsigned short f2bf(float f) {
  unsigned u = __float_as_uint(f);
  u += 0x7fffu + ((u >> 16) & 1u);   // RNE round to bf16
  return (unsigned short)(u >> 16);
}
__device__ __forceinline__ unsigned umax_(unsigned a, unsigned b) { return a > b ? a : b; }

// ---- fused prep(emb->bf16 + half||e||^2) + prez(z -> row-major bf16 + sum z^2)
__global__ __launch_bounds__(256) void k_pre(const float* __restrict__ z,
                                             const float* __restrict__ emb,
                                             unsigned short* __restrict__ embb,
                                             float* __restrict__ h2,
                                             unsigned short* __restrict__ zb,
                                             float* __restrict__ acc) {
  __shared__ unsigned lds[64 * 128];
  __shared__ float rsum[4];
  const int t = threadIdx.x;
  const int bid = blockIdx.x;

  if (bid >= 512) {            // ---- prep branch (128 blocks) ----
    const int n = (bid - 512) * 8 + (t >> 5);
    const int c0 = (t & 31) * 8;
    const float* src = emb + (size_t)n * 256 + c0;
    float s = 0.f;
    union { bf16x8 v; unsigned short u[8]; } pk;
#pragma unroll
    for (int i = 0; i < 8; ++i) {
      float f = src[i];
      s += f * f;
      pk.u[i] = f2bf(f);
    }
    *(bf16x8*)(embb + (size_t)n * 256 + c0) = pk.v;
#pragma unroll
    for (int m = 1; m < 32; m <<= 1) s += __shfl_xor(s, m);
    if ((t & 31) == 0) h2[n] = 0.5f * s;
    return;
  }

  // ---- prez branch (512 blocks): 64 hw-rows x 256 c ----
  const int b = bid >> 4, hwg = bid & 15;
  const int tc = t >> 4, h4 = (t & 15) * 4;
  const float* zp = z + (size_t)b * 262144 + hwg * 64;
  float ss = 0.f;
#pragma unroll
  for (int p = 0; p < 8; ++p) {
    const int cp = p * 16 + tc;                       // c-pair index 0..127
    const float4 v0 = *(const float4*)(zp + (size_t)(2 * cp) * 1024 + h4);
    const float4 v1 = *(const float4*)(zp + (size_t)(2 * cp + 1) * 1024 + h4);
    ss += v0.x * v0.x + v0.y * v0.y + v0.z * v0.z + v0.w * v0.w
        + v1.x * v1.x + v1.y * v1.y + v1.z * v1.z + v1.w * v1.w;
    const unsigned w0 = ((unsigned)f2bf(v1.x) << 16) | (unsigned)f2bf(v0.x);
    const unsigned w1 = ((unsigned)f2bf(v1.y) << 16) | (unsigned)f2bf(v0.y);
    const unsigned w2 = ((unsigned)f2bf(v1.z) << 16) | (unsigned)f2bf(v0.z);
    const unsigned w3 = ((unsigned)f2bf(v1.w) << 16) | (unsigned)f2bf(v0.w);
    lds[(h4 + 0) * 128 + (cp ^ ((h4 + 0) & 31))] = w0;
    lds[(h4 + 1) * 128 + (cp ^ ((h4 + 1) & 31))] = w1;
    lds[(h4 + 2) * 128 + (cp ^ ((h4 + 2) & 31))] = w2;
    lds[(h4 + 3) * 128 + (cp ^ ((h4 + 3) & 31))] = w3;
  }
#pragma unroll
  for (int m = 1; m < 64; m <<= 1) ss += __shfl_xor(ss, m);
  if ((t & 63) == 0) rsum[t >> 6] = ss;
  __syncthreads();
  if (t == 0) atomicAdd(acc, rsum[0] + rsum[1] + rsum[2] + rsum[3]);

  unsigned* zbd = (unsigned*)zb;
  const size_t tb = ((size_t)b * 1024 + hwg * 64) * 128;   // dword index
#pragma unroll
  for (int s = 0; s < 8; ++s) {
    const int r = s * 8 + (t >> 5);
    const int d0 = (t & 31) * 4;
    uint4 v;
    v.x = lds[r * 128 + ((d0 + 0) ^ (r & 31))];
    v.y = lds[r * 128 + ((d0 + 1) ^ (r & 31))];
    v.z = lds[r * 128 + ((d0 + 2) ^ (r & 31))];
    v.w = lds[r * 128 + ((d0 + 3) ^ (r & 31))];
    *(uint4*)(zbd + tb + (size_t)s * 1024 + (size_t)t * 4) = v;
  }
}

// ---- main: B(64 emb) in LDS once, A streamed global->reg with 1-deep prefetch
// grid 1024 = 16 ch x 64 rg (bid = ch*64+rg -> same rg same XCD), 4 blocks/CU.
__global__ __launch_bounds__(256, 4) void k_main(
    const unsigned short* __restrict__ zb, const unsigned short* __restrict__ embb,
    const float* __restrict__ h2, unsigned* __restrict__ best) {

  __shared__ __align__(16) unsigned short lB[64 * 256];   // 32 KB

  const int t = threadIdx.x;
  const int lane = t & 63;
  const int w = t >> 6;
  const int l15 = lane & 15;
  const int l4 = lane >> 4;
  const int rg = blockIdx.x & 63;
  const int ch = blockIdx.x >> 6;
  const int cb = ch * 64;

  {
    const unsigned short* base = embb + (size_t)cb * 256;
#pragma unroll
    for (int rd = 0; rd < 8; ++rd) {
      const int nl = rd * 8 + (t >> 5);
      const int p = t & 31;
      const int kc = p ^ (nl & 7);
      const unsigned short* g = base + (size_t)nl * 256 + kc * 8;
      char* l = (char*)lB + rd * 4096 + w * 1024;
      __builtin_amdgcn_global_load_lds((const __attribute__((address_space(1))) void*)g,
                                       (__attribute__((address_space(3))) void*)l,
                                       16, 0, 0);
    }
  }
  float hneg[4];
  unsigned cio[4];
#pragma unroll
  for (int ni = 0; ni < 4; ++ni) {
    hneg[ni] = -1.0f - h2[cb + ni * 16 + l15];   // shift scores to t-1 < 0
    cio[ni] = (unsigned)(1023 - (cb + ni * 16 + l15));
  }
  asm volatile("s_waitcnt vmcnt(0)" ::: "memory");
  __syncthreads();   // the only barrier

  const char* Az = (const char*)zb + ((size_t)(rg * 512 + w * 128) + l15) * 512 + l4 * 16;
  const int rowb0 = rg * 512 + w * 128;

#pragma unroll
  for (int g = 0; g < 2; ++g) {
    const char* ag = Az + (size_t)g * 64 * 512;
    f32x4 acc[4][4];
#pragma unroll
    for (int mi = 0; mi < 4; ++mi)
#pragma unroll
      for (int ni = 0; ni < 4; ++ni)
#pragma unroll
        for (int q = 0; q < 4; ++q) acc[mi][ni][q] = hneg[ni];

    bf16x8 aC[4], aN[4];
#pragma unroll
    for (int mi = 0; mi < 4; ++mi) aC[mi] = *(const bf16x8*)(ag + mi * 8192);

#pragma unroll
    for (int kk = 0; kk < 8; ++kk) {
      if (kk < 7) {
#pragma unroll
        for (int mi = 0; mi < 4; ++mi)
          aN[mi] = *(const bf16x8*)(ag + mi * 8192 + (kk + 1) * 64);
      }
#pragma unroll
      for (int ni = 0; ni < 4; ++ni) {
        const int n = ni * 16 + l15;
        const int p = (kk * 4 + l4) ^ (n & 7);
        const bf16x8 bf = *(const bf16x8*)((const char*)lB + n * 512 + p * 16);
        acc[0][ni] = __builtin_amdgcn_mfma_f32_16x16x32_bf16(aC[0], bf, acc[0][ni], 0, 0, 0);
        acc[1][ni] = __builtin_amdgcn_mfma_f32_16x16x32_bf16(aC[1], bf, acc[1][ni], 0, 0, 0);
        acc[2][ni] = __builtin_amdgcn_mfma_f32_16x16x32_bf16(aC[2], bf, acc[2][ni], 0, 0, 0);
        acc[3][ni] = __builtin_amdgcn_mfma_f32_16x16x32_bf16(aC[3], bf, acc[3][ni], 0, 0, 0);
      }
      if (kk < 7) {
#pragma unroll
        for (int mi = 0; mi < 4; ++mi) aC[mi] = aN[mi];
      }
    }

    // fold: all scores < 0 -> key = ~bits is monotone; pack idx in low 10 bits
#pragma unroll
    for (int mi = 0; mi < 4; ++mi)
#pragma unroll
      for (int j = 0; j < 4; ++j) {
        unsigned kb = (~__float_as_uint(acc[mi][0][j]) & 0xFFFFFC00u) | cio[0];
        kb = umax_(kb, (~__float_as_uint(acc[mi][1][j]) & 0xFFFFFC00u) | cio[1]);
        kb = umax_(kb, (~__float_as_uint(acc[mi][2][j]) & 0xFFFFFC00u) | cio[2]);
        kb = umax_(kb, (~__float_as_uint(acc[mi][3][j]) & 0xFFFFFC00u) | cio[3]);
        // 16-lane reduce on VALU via DPP: xor1, xor2, half_mirror(^7), mirror(^15)
        kb = umax_(kb, (unsigned)__builtin_amdgcn_update_dpp(0, (int)kb, 0xB1, 0xF, 0xF, true));
        kb = umax_(kb, (unsigned)__builtin_amdgcn_update_dpp(0, (int)kb, 0x4E, 0xF, 0xF, true));
        kb = umax_(kb, (unsigned)__builtin_amdgcn_update_dpp(0, (int)kb, 0x141, 0xF, 0xF, true));
        kb = umax_(kb, (unsigned)__builtin_amdgcn_update_dpp(0, (int)kb, 0x140, 0xF, 0xF, true));
        if (l15 == 0) atomicMax(&best[rowb0 + g * 64 + mi * 16 + l4 * 4 + j], kb);
      }
  }
}

// ---- final: decode best, gather emb, transposed write, loss (+last-block fin)
__global__ __launch_bounds__(256) void k_final(const unsigned* __restrict__ best,
                                               const float* __restrict__ emb,
                                               float* __restrict__ out,
                                               float* __restrict__ acc,
                                               unsigned* __restrict__ done2,
                                               float* __restrict__ lossp) {
  __shared__ int sidx[64];
  __shared__ float lds[64 * 68];
  const int t = threadIdx.x;
  const int lane = t & 63;
  const int w = t >> 6;
  const int l15 = lane & 15;
  const int l4 = lane >> 4;
  const int b = blockIdx.x >> 4, hwg = blockIdx.x & 15;
  const int rowb = b * 1024 + hwg * 64;

  if (t < 64) {
    const unsigned p = best[rowb + t];
    sidx[t] = 1023 - (int)(p & 1023u);
    float s = __uint_as_float(~p) + 1.0f;   // decode t' and unshift
#pragma unroll
    for (int m = 1; m < 64; m <<= 1) s += __shfl_xor(s, m);
    if (t == 0) atomicAdd(acc, -2.f * s);
  }
  __syncthreads();

  const int hw = t & 63, cq = t >> 6;
  const float* ep = emb + (size_t)sidx[hw] * 256;
  float* ob = out + (size_t)b * 262144 + hwg * 64;
#pragma unroll
  for (int cc = 0; cc < 4; ++cc) {
    const int c0 = cc * 64 + cq * 16;
#pragma unroll
    for (int i = 0; i < 4; ++i) {
      const float4 v = *(const float4*)(ep + c0 + i * 4);
      lds[(cq * 16 + i * 4 + 0) * 68 + hw] = v.x;
      lds[(cq * 16 + i * 4 + 1) * 68 + hw] = v.y;
      lds[(cq * 16 + i * 4 + 2) * 68 + hw] = v.z;
      lds[(cq * 16 + i * 4 + 3) * 68 + hw] = v.w;
    }
    __syncthreads();
#pragma unroll
    for (int i = 0; i < 4; ++i) {
      const int c = w * 16 + i * 4 + l4;
      const float4 vv = *(const float4*)(&lds[c * 68 + l15 * 4]);
      *(float4*)(ob + (size_t)(cc * 64 + c) * 1024 + l15 * 4) = vv;
    }
    __syncthreads();
  }

  if (t == 0) {
    __threadfence();
    const unsigned old = atomicAdd(done2, 1u);
    if (old == 511u) {
      const float tot = atomicAdd(acc, 0.f);   // coherent read after all adds
      lossp[0] = 1.25f * tot * (1.0f / 8388608.0f);
    }
  }
}

extern "C" void kernel_launch(void* const* d_in, const int* in_sizes, int n_in,
                              void* d_out, int out_size, void* d_ws, size_t ws_size,
                              hipStream_t stream) {
  (void)in_sizes; (void)n_in; (void)ws_size;
  const float* z   = (const float*)d_in[0];
  const float* emb = (const float*)d_in[1];
  float* out = (float*)d_out;
  char* ws = (char*)d_ws;
  unsigned short* embb = (unsigned short*)ws;                    // 512 KB
  float* h2    = (float*)(ws + 524288);                          // 4 KB
  float* acc   = (float*)(ws + 528384);                          // 4 B
  unsigned* done2 = (unsigned*)(ws + 528388);                    // 4 B
  unsigned short* zb = (unsigned short*)(ws + (1 << 20));        // 16 MB
  unsigned* best = (unsigned*)(ws + (1 << 20) + 16777216);       // 256 KB

  hipMemsetAsync(ws + 528384, 0, 8, stream);
  hipMemsetAsync(best, 0, 262144, stream);
  hipLaunchKernelGGL(k_pre, dim3(640), dim3(256), 0, stream, z, emb, embb, h2, zb, acc);
  hipLaunchKernelGGL(k_main, dim3(1024), dim3(256), 0, stream, zb, embb, h2, best);
  hipLaunchKernelGGL(k_final, dim3(512), dim3(256), 0, stream, best, emb, out, acc, done2,
                     out + (size_t)out_size - 1);
}